// Round 3
// 849.874 us; speedup vs baseline: 1.1064x; 1.1064x over previous
//
#include <hip/hip_runtime.h>
#include <cstdint>
#include <cstddef>

#define NNODES 100000
#define NEDGES 1600000
// D = 128, C = 128 (hard-coded below)

typedef short bf16x8 __attribute__((ext_vector_type(8)));
typedef float f32x4 __attribute__((ext_vector_type(4)));
// native fp16 (no hip_fp16.h dependency — clang _Float16 maps to v_cvt_f16_f32/v_cvt_f32_f16)
typedef _Float16 f16x2 __attribute__((ext_vector_type(2)));
typedef _Float16 f16x4 __attribute__((ext_vector_type(4)));

// ---------------------------------------------------------------- bf16 split helpers

__device__ __forceinline__ unsigned short bf16_rne(float x) {
  unsigned int u = __float_as_uint(x);
  unsigned int r = u + 0x7FFFu + ((u >> 16) & 1u);
  return (unsigned short)(r >> 16);
}
__device__ __forceinline__ float bf16_to_f(unsigned short h) {
  return __uint_as_float(((unsigned int)h) << 16);
}

// ---------------------------------------------------------------- utilities

__global__ void zero_int_kernel(int* __restrict__ p, int n) {
  int i = blockIdx.x * blockDim.x + threadIdx.x;
  if (i < n) p[i] = 0;
}

// int64 vs int32 edge_index detection (high words all zero => int64)
__global__ void detect_kernel(const unsigned int* __restrict__ ei, int* __restrict__ flag) {
  unsigned int v = ei[2 * threadIdx.x + 1];
  unsigned long long b = __ballot(v != 0u);
  if (threadIdx.x == 0) *flag = (b == 0ull) ? 1 : 0;
}

__device__ __forceinline__ int edge_val(const void* ei, int is64, long long idx) {
  if (is64) return (int)((const long long*)ei)[idx];
  return ((const int*)ei)[idx];
}

// ---------------------------------------------------------------- degree / CSR

__global__ void hist_kernel(const void* __restrict__ ei, const int* __restrict__ flag,
                            int* __restrict__ counts) {
  const int is64 = *flag;
  for (long long e = (long long)blockIdx.x * blockDim.x + threadIdx.x; e < NEDGES;
       e += (long long)gridDim.x * blockDim.x) {
    int d = edge_val(ei, is64, NEDGES + e);
    atomicAdd(&counts[d], 1);
  }
}

__global__ void dinv_kernel(const int* __restrict__ counts, float* __restrict__ dinv) {
  int i = blockIdx.x * blockDim.x + threadIdx.x;
  if (i < NNODES) dinv[i] = rsqrtf((float)(counts[i] + 1));  // +1 self loop
}

#define SCAN_B 256
#define SCAN_TILE 1024

__global__ void scan_reduce_kernel(const int* __restrict__ counts, int* __restrict__ bsums) {
  __shared__ int sd[SCAN_B];
  int t = threadIdx.x;
  int base = blockIdx.x * SCAN_TILE + t * 4;
  int s = 0;
#pragma unroll
  for (int i = 0; i < 4; i++) {
    int idx = base + i;
    if (idx < NNODES) s += counts[idx];
  }
  sd[t] = s;
  __syncthreads();
  for (int o = SCAN_B / 2; o > 0; o >>= 1) {
    if (t < o) sd[t] += sd[t + o];
    __syncthreads();
  }
  if (t == 0) bsums[blockIdx.x] = sd[0];
}

__global__ void scan_bsums_kernel(int* __restrict__ bsums, int* __restrict__ offs, int nb) {
  if (threadIdx.x == 0 && blockIdx.x == 0) {
    int run = 0;
    for (int b = 0; b < nb; b++) {
      int v = bsums[b];
      bsums[b] = run;
      run += v;
    }
    offs[NNODES] = run;
  }
}

__global__ void scan_write_kernel(const int* __restrict__ counts, const int* __restrict__ bsums,
                                  int* __restrict__ offs) {
  __shared__ int sd[SCAN_B];
  int t = threadIdx.x;
  int base = blockIdx.x * SCAN_TILE + t * 4;
  int v[4];
  int s = 0;
#pragma unroll
  for (int i = 0; i < 4; i++) {
    int idx = base + i;
    v[i] = (idx < NNODES) ? counts[idx] : 0;
    s += v[i];
  }
  sd[t] = s;
  __syncthreads();
  for (int o = 1; o < SCAN_B; o <<= 1) {
    int x = (t >= o) ? sd[t - o] : 0;
    __syncthreads();
    sd[t] += x;
    __syncthreads();
  }
  int run = sd[t] - s + bsums[blockIdx.x];
#pragma unroll
  for (int i = 0; i < 4; i++) {
    int idx = base + i;
    if (idx < NNODES) {
      offs[idx] = run;
      run += v[i];
    }
  }
}

__global__ void fill_kernel(const void* __restrict__ ei, const int* __restrict__ flag,
                            const int* __restrict__ offs, int* __restrict__ fillc,
                            int* __restrict__ csr) {
  const int is64 = *flag;
  for (long long e = (long long)blockIdx.x * blockDim.x + threadIdx.x; e < NEDGES;
       e += (long long)gridDim.x * blockDim.x) {
    int s = edge_val(ei, is64, e);
    int d = edge_val(ei, is64, NEDGES + e);
    int pos = offs[d] + atomicAdd(&fillc[d], 1);
    csr[pos] = s;
  }
}

// ---------------------------------------------------------------- prescale (fp16 out)
// y[i,:] = (fp16) dinv[i] * x[i,:]

__global__ void prescale_half_kernel(const float* __restrict__ x, const float* __restrict__ dinv,
                                     f16x4* __restrict__ y) {
  int i = blockIdx.x * blockDim.x + threadIdx.x;  // over NNODES*32 float4
  if (i >= NNODES * 32) return;
  int row = i >> 5;
  float s = dinv[row];
  float4 v = ((const float4*)x)[i];
  f16x4 h;
  h[0] = (_Float16)(v.x * s);
  h[1] = (_Float16)(v.y * s);
  h[2] = (_Float16)(v.z * s);
  h[3] = (_Float16)(v.w * s);
  y[i] = h;
}

// ---------------------------------------------------------------- aggregation (gather, fp16 in)
// Input rows are PRE-SCALED fp16: y_j = (fp16)(dinv[j]*x_j).   256 B/row instead of 512.
// out[i,:] = dinv[i] * (y_i + sum_{j in nbr(i)} y_j) + bias   (fp32 accumulate / fp32 out)
// One wave per node, f16x2 per lane, 8-way unrolled gathers (4 fp32 accumulators).

__device__ __forceinline__ float2 f16x2_to_f32(f16x2 h) {
  return make_float2((float)h[0], (float)h[1]);
}

__global__ __launch_bounds__(256) void aggregate_half_kernel(
    const f16x2* __restrict__ in, float* __restrict__ out, const int* __restrict__ offs,
    const int* __restrict__ csr, const float* __restrict__ dinv, const float* __restrict__ bias) {
  int node = blockIdx.x * 4 + (threadIdx.x >> 6);
  if (node >= NNODES) return;
  int ch = threadIdx.x & 63;  // f16x2 index within row (64 x f16x2 = 128 cols)
  int beg = offs[node], end = offs[node + 1];

  // self term (pre-scaled row)
  float2 a0 = f16x2_to_f32(in[(size_t)node * 64 + ch]);
  float2 a1 = make_float2(0.f, 0.f);
  float2 a2 = make_float2(0.f, 0.f);
  float2 a3 = make_float2(0.f, 0.f);

  int p = beg;
  for (; p + 8 <= end; p += 8) {
    int j0 = csr[p + 0], j1 = csr[p + 1], j2 = csr[p + 2], j3 = csr[p + 3];
    int j4 = csr[p + 4], j5 = csr[p + 5], j6 = csr[p + 6], j7 = csr[p + 7];
    f16x2 h0 = in[(size_t)j0 * 64 + ch];
    f16x2 h1 = in[(size_t)j1 * 64 + ch];
    f16x2 h2 = in[(size_t)j2 * 64 + ch];
    f16x2 h3 = in[(size_t)j3 * 64 + ch];
    f16x2 h4 = in[(size_t)j4 * 64 + ch];
    f16x2 h5 = in[(size_t)j5 * 64 + ch];
    f16x2 h6 = in[(size_t)j6 * 64 + ch];
    f16x2 h7 = in[(size_t)j7 * 64 + ch];
    float2 v0 = f16x2_to_f32(h0);
    float2 v1 = f16x2_to_f32(h1);
    float2 v2 = f16x2_to_f32(h2);
    float2 v3 = f16x2_to_f32(h3);
    float2 v4 = f16x2_to_f32(h4);
    float2 v5 = f16x2_to_f32(h5);
    float2 v6 = f16x2_to_f32(h6);
    float2 v7 = f16x2_to_f32(h7);
    a0.x += v0.x; a0.y += v0.y;
    a1.x += v1.x; a1.y += v1.y;
    a2.x += v2.x; a2.y += v2.y;
    a3.x += v3.x; a3.y += v3.y;
    a0.x += v4.x; a0.y += v4.y;
    a1.x += v5.x; a1.y += v5.y;
    a2.x += v6.x; a2.y += v6.y;
    a3.x += v7.x; a3.y += v7.y;
  }
  for (; p + 2 <= end; p += 2) {
    int j0 = csr[p], j1 = csr[p + 1];
    float2 v0 = f16x2_to_f32(in[(size_t)j0 * 64 + ch]);
    float2 v1 = f16x2_to_f32(in[(size_t)j1 * 64 + ch]);
    a0.x += v0.x; a0.y += v0.y;
    a1.x += v1.x; a1.y += v1.y;
  }
  if (p < end) {
    float2 v0 = f16x2_to_f32(in[(size_t)csr[p] * 64 + ch]);
    a0.x += v0.x; a0.y += v0.y;
  }

  float di = dinv[node];
  int c = ch * 2;
  float2 r;
  r.x = di * (a0.x + a1.x + a2.x + a3.x);
  r.y = di * (a0.y + a1.y + a2.y + a3.y);
  if (bias) {
    r.x += bias[c];
    r.y += bias[c + 1];
  }
  *(float2*)(out + (size_t)node * 128 + c) = r;
}

// ---------------------------------------------------------------- weight prep
// W [K][M] fp32  ->  Wt_hi/Wt_lo [M][K] bf16 (transposed, split)

__global__ void wprep_kernel(const float* __restrict__ W, int K, int M,
                             unsigned short* __restrict__ th, unsigned short* __restrict__ tl) {
  int i = blockIdx.x * blockDim.x + threadIdx.x;
  if (i >= K * M) return;
  int k = i / M, m = i - k * M;
  float x = W[i];
  unsigned short h = bf16_rne(x);
  float lo = x - bf16_to_f(h);
  th[(size_t)m * K + k] = h;
  tl[(size_t)m * K + k] = bf16_rne(lo);
}

// ---------------------------------------------------------------- bf16x3 split MFMA GEMM
// C[n,M] = concat(A0,A1,A2) @ W (+row_scale)(+bias)(+relu), fp32 in, fp32 or fp16 out:
// x*w ~= xh*wh + xh*wl + xl*wh (fp32 MFMA accumulation). Error ~2^-16 relative.
// Block 128x128, BK=32, 4 waves each 64x64 (4x4 tiles of 16x16x32 MFMA).
// row_scale (optional): C[r,:] *= row_scale[r] before bias — used to fold the
// dinv pre-scale of the next aggregation into this GEMM's epilogue for free.
// out_half: write _Float16 output (feeds the fp16 aggregation path).

#define BM 128
#define BN 128
#define BK 32
#define LDT 40

__global__ __launch_bounds__(256) void gemm_mfma_kernel(
    const float* __restrict__ A0, int K0, const float* __restrict__ A1, int K1,
    const float* __restrict__ A2, int K2, const unsigned short* __restrict__ Bth,
    const unsigned short* __restrict__ Btl, int Ktot, int M, const float* __restrict__ bias,
    const float* __restrict__ row_scale, float* __restrict__ Cmat, int relu, int out_half,
    int nrows) {
  __shared__ unsigned short As_hi[BM * LDT];
  __shared__ unsigned short As_lo[BM * LDT];
  __shared__ unsigned short Bs_hi[BN * LDT];
  __shared__ unsigned short Bs_lo[BN * LDT];

  const int tid = threadIdx.x;
  const int lane = tid & 63;
  const int wv = tid >> 6;
  const int mBase = (wv >> 1) * 64;
  const int nBase = (wv & 1) * 64;
  const int ml = lane & 15;
  const int quad = lane >> 4;
  const int rowBase = blockIdx.x * BM;
  const int colBase = blockIdx.y * BN;

  const int sr = tid >> 1;        // 0..127
  const int skc = (tid & 1) * 16; // 0 or 16

  f32x4 acc[4][4];
  const f32x4 zero = {0.f, 0.f, 0.f, 0.f};
#pragma unroll
  for (int i = 0; i < 4; i++)
#pragma unroll
    for (int j = 0; j < 4; j++) acc[i][j] = zero;

  for (int k0 = 0; k0 < Ktot; k0 += BK) {
    const float* Ap;
    int kl, Kp;
    if (k0 < K0) {
      Ap = A0; kl = k0; Kp = K0;
    } else if (k0 < K0 + K1) {
      Ap = A1; kl = k0 - K0; Kp = K1;
    } else {
      Ap = A2; kl = k0 - K0 - K1; Kp = K2;
    }
    {
      int gr = rowBase + sr;
      float4 v[4];
      if (gr < nrows) {
        const float4* src = (const float4*)(Ap + (size_t)gr * Kp + kl + skc);
#pragma unroll
        for (int i = 0; i < 4; i++) v[i] = src[i];
      } else {
#pragma unroll
        for (int i = 0; i < 4; i++) v[i] = make_float4(0.f, 0.f, 0.f, 0.f);
      }
      unsigned short hb[16], lb[16];
      const float* vf = (const float*)v;
#pragma unroll
      for (int i = 0; i < 16; i++) {
        float x = vf[i];
        unsigned short h = bf16_rne(x);
        hb[i] = h;
        lb[i] = bf16_rne(x - bf16_to_f(h));
      }
      *(uint4*)&As_hi[sr * LDT + skc] = *(uint4*)&hb[0];
      *(uint4*)&As_hi[sr * LDT + skc + 8] = *(uint4*)&hb[8];
      *(uint4*)&As_lo[sr * LDT + skc] = *(uint4*)&lb[0];
      *(uint4*)&As_lo[sr * LDT + skc + 8] = *(uint4*)&lb[8];

      const unsigned short* bh = Bth + (size_t)(colBase + sr) * Ktot + k0 + skc;
      const unsigned short* bl = Btl + (size_t)(colBase + sr) * Ktot + k0 + skc;
      uint4 u0 = ((const uint4*)bh)[0];
      uint4 u1 = ((const uint4*)bh)[1];
      uint4 w0 = ((const uint4*)bl)[0];
      uint4 w1 = ((const uint4*)bl)[1];
      *(uint4*)&Bs_hi[sr * LDT + skc] = u0;
      *(uint4*)&Bs_hi[sr * LDT + skc + 8] = u1;
      *(uint4*)&Bs_lo[sr * LDT + skc] = w0;
      *(uint4*)&Bs_lo[sr * LDT + skc + 8] = w1;
    }
    __syncthreads();

    bf16x8 ah[4], al[4], bh[4], bl[4];
#pragma unroll
    for (int nt = 0; nt < 4; nt++) {
      int nrow = nBase + nt * 16 + ml;
      bh[nt] = *(const bf16x8*)&Bs_hi[nrow * LDT + quad * 8];
      bl[nt] = *(const bf16x8*)&Bs_lo[nrow * LDT + quad * 8];
    }
#pragma unroll
    for (int mt = 0; mt < 4; mt++) {
      int mrow = mBase + mt * 16 + ml;
      ah[mt] = *(const bf16x8*)&As_hi[mrow * LDT + quad * 8];
      al[mt] = *(const bf16x8*)&As_lo[mrow * LDT + quad * 8];
    }
#pragma unroll
    for (int mt = 0; mt < 4; mt++)
#pragma unroll
      for (int nt = 0; nt < 4; nt++) {
        acc[mt][nt] = __builtin_amdgcn_mfma_f32_16x16x32_bf16(ah[mt], bh[nt], acc[mt][nt], 0, 0, 0);
        acc[mt][nt] = __builtin_amdgcn_mfma_f32_16x16x32_bf16(ah[mt], bl[nt], acc[mt][nt], 0, 0, 0);
        acc[mt][nt] = __builtin_amdgcn_mfma_f32_16x16x32_bf16(al[mt], bh[nt], acc[mt][nt], 0, 0, 0);
      }
    __syncthreads();
  }

  // epilogue: C/D layout col=lane&15, row=quad*4+reg
#pragma unroll
  for (int nt = 0; nt < 4; nt++) {
    int col = colBase + nBase + nt * 16 + ml;
    float bv = bias ? bias[col] : 0.f;
#pragma unroll
    for (int mt = 0; mt < 4; mt++) {
      int row0 = rowBase + mBase + mt * 16 + quad * 4;
#pragma unroll
      for (int r = 0; r < 4; r++) {
        int grow = row0 + r;
        if (grow >= nrows) continue;
        float v = acc[mt][nt][r];
        if (row_scale) v *= row_scale[grow];
        v += bv;
        if (relu) v = fmaxf(v, 0.f);
        if (out_half) {
          ((_Float16*)Cmat)[(size_t)grow * M + col] = (_Float16)v;
        } else {
          Cmat[(size_t)grow * M + col] = v;
        }
      }
    }
  }
}

// ---------------------------------------------------------------- launch

extern "C" void kernel_launch(void* const* d_in, const int* in_sizes, int n_in, void* d_out,
                              int out_size, void* d_ws, size_t ws_size, hipStream_t stream) {
  const float* x_self     = (const float*)d_in[0];
  const float* x_neighbor = (const float*)d_in[1];
  const void*  edge_index = d_in[2];
  const float* W_in_self  = (const float*)d_in[3];
  const float* b_in_self  = (const float*)d_in[4];
  const float* W_out_self = (const float*)d_in[5];
  const float* b_out_self = (const float*)d_in[6];
  const float* Wg1        = (const float*)d_in[7];
  const float* bg1        = (const float*)d_in[8];
  const float* Wg2        = (const float*)d_in[9];
  const float* bg2        = (const float*)d_in[10];
  const float* W_out      = (const float*)d_in[11];
  const float* b_out      = (const float*)d_in[12];
  float* out = (float*)d_out;

  char* ws = (char*)d_ws;
  size_t off = 0;
  auto alloc = [&](size_t bytes) -> void* {
    void* p = ws + off;
    off = (off + bytes + 255) & ~(size_t)255;
    return p;
  };
  int* counts = (int*)alloc((size_t)2 * NNODES * 4);  // counts + fillc contiguous
  int* fillc  = counts + NNODES;
  int*   offs   = (int*)alloc((size_t)(NNODES + 1) * 4);
  int*   csr    = (int*)alloc((size_t)NEDGES * 4);
  int*   bsums  = (int*)alloc(4096);
  int*   flag   = (int*)alloc(256);
  float* dinv   = (float*)alloc((size_t)NNODES * 4);
  unsigned short* wt1h = (unsigned short*)alloc(32768 * 2);  // W_in_self  K=128 M=256
  unsigned short* wt1l = (unsigned short*)alloc(32768 * 2);
  unsigned short* wt2h = (unsigned short*)alloc(49152 * 2);  // W_out_self K=384 M=128
  unsigned short* wt2l = (unsigned short*)alloc(49152 * 2);
  unsigned short* wt3h = (unsigned short*)alloc(32768 * 2);  // Wg1        K=128 M=256
  unsigned short* wt3l = (unsigned short*)alloc(32768 * 2);
  unsigned short* wt4h = (unsigned short*)alloc(32768 * 2);  // Wg2        K=256 M=128
  unsigned short* wt4l = (unsigned short*)alloc(32768 * 2);
  unsigned short* wt5h = (unsigned short*)alloc(65536 * 2);  // W_out      K=512 M=128
  unsigned short* wt5l = (unsigned short*)alloc(65536 * 2);
  float* bufA = (float*)alloc((size_t)NNODES * 256 * 4);
  float* bufB = (float*)alloc((size_t)NNODES * 256 * 4);
  (void)ws_size;

  const int nb = (NNODES + SCAN_TILE - 1) / SCAN_TILE;  // 98
  const int gridRows = (NNODES + BM - 1) / BM;          // 782

  detect_kernel<<<1, 64, 0, stream>>>((const unsigned int*)edge_index, flag);
  zero_int_kernel<<<(2 * NNODES + 255) / 256, 256, 0, stream>>>(counts, 2 * NNODES);
  hist_kernel<<<1024, 256, 0, stream>>>(edge_index, flag, counts);
  dinv_kernel<<<(NNODES + 255) / 256, 256, 0, stream>>>(counts, dinv);
  scan_reduce_kernel<<<nb, SCAN_B, 0, stream>>>(counts, bsums);
  scan_bsums_kernel<<<1, 64, 0, stream>>>(bsums, offs, nb);
  scan_write_kernel<<<nb, SCAN_B, 0, stream>>>(counts, bsums, offs);
  fill_kernel<<<1024, 256, 0, stream>>>(edge_index, flag, offs, fillc, csr);

  wprep_kernel<<<(32768 + 255) / 256, 256, 0, stream>>>(W_in_self, 128, 256, wt1h, wt1l);
  wprep_kernel<<<(49152 + 255) / 256, 256, 0, stream>>>(W_out_self, 384, 128, wt2h, wt2l);
  wprep_kernel<<<(32768 + 255) / 256, 256, 0, stream>>>(Wg1, 128, 256, wt3h, wt3l);
  wprep_kernel<<<(32768 + 255) / 256, 256, 0, stream>>>(Wg2, 256, 128, wt4h, wt4l);
  wprep_kernel<<<(65536 + 255) / 256, 256, 0, stream>>>(W_out, 512, 128, wt5h, wt5l);

  // ---- dense self branch ----
  gemm_mfma_kernel<<<dim3(gridRows, 2), 256, 0, stream>>>(
      x_self, 128, nullptr, 0, nullptr, 0, wt1h, wt1l, 128, 256, b_in_self, nullptr, bufA, 1, 0,
      NNODES);
  gemm_mfma_kernel<<<dim3(gridRows, 1), 256, 0, stream>>>(
      x_self, 128, bufA, 256, nullptr, 0, wt2h, wt2l, 384, 128, b_out_self, nullptr, out, 0, 0,
      NNODES);

  // ---- GCN branch (A_norm @ (X W) == (A_norm @ X) W) ----
  // Buffer timeline: ybuf=bufB[0:N*128 halves] (consumed by agg1 before GEMM-3 overwrites bufB)
  _Float16* ybuf = (_Float16*)bufB;           // [N,128] fp16 pre-scaled x_neighbor
  float* aggx  = bufA;                        // [N,128] fp32 (bufA free after GEMM-2)
  float* g1    = bufB;                        // [N,256] fp32
  _Float16* xw2 = (_Float16*)bufA;            // [N,128] fp16 (aggx dead after GEMM-3)
  float* g2    = bufA + (size_t)NNODES * 128; // [N,128] fp32 (no overlap with xw2: 25.6MB < 51.2MB)

  prescale_half_kernel<<<(NNODES * 32 + 255) / 256, 256, 0, stream>>>(x_neighbor, dinv,
                                                                     (f16x4*)ybuf);
  aggregate_half_kernel<<<NNODES / 4, 256, 0, stream>>>((const f16x2*)ybuf, aggx, offs, csr,
                                                        dinv, nullptr);
  gemm_mfma_kernel<<<dim3(gridRows, 2), 256, 0, stream>>>(
      aggx, 128, nullptr, 0, nullptr, 0, wt3h, wt3l, 128, 256, bg1, nullptr, g1, 0, 0, NNODES);
  // xw2 = (fp16)((g1 @ Wg2) * dinv[row])  (pre-scale for agg2 folded into epilogue, fp16 out)
  gemm_mfma_kernel<<<dim3(gridRows, 1), 256, 0, stream>>>(
      g1, 256, nullptr, 0, nullptr, 0, wt4h, wt4l, 256, 128, nullptr, dinv, (float*)xw2, 0, 1,
      NNODES);
  aggregate_half_kernel<<<NNODES / 4, 256, 0, stream>>>((const f16x2*)xw2, g2, offs, csr, dinv,
                                                        bg2);
  gemm_mfma_kernel<<<dim3(gridRows, 1), 256, 0, stream>>>(
      x_neighbor, 128, g1, 256, g2, 128, wt5h, wt5l, 512, 128, b_out, nullptr,
      out + (size_t)NNODES * 128, 0, 0, NNODES);
}

// Round 4
// 800.041 us; speedup vs baseline: 1.1754x; 1.0623x over previous
//
#include <hip/hip_runtime.h>
#include <cstdint>
#include <cstddef>

#define NNODES 100000
#define NEDGES 1600000
// D = 128, C = 128 (hard-coded below)

typedef float f32x4 __attribute__((ext_vector_type(4)));
// native fp16 (no hip_fp16.h dependency — clang _Float16)
typedef _Float16 f16x2 __attribute__((ext_vector_type(2)));
typedef _Float16 f16x4 __attribute__((ext_vector_type(4)));
typedef _Float16 f16x8 __attribute__((ext_vector_type(8)));

// ---------------------------------------------------------------- utilities

__global__ void zero_int_kernel(int* __restrict__ p, int n) {
  int i = blockIdx.x * blockDim.x + threadIdx.x;
  if (i < n) p[i] = 0;
}

// int64 vs int32 edge_index detection (high words all zero => int64)
__global__ void detect_kernel(const unsigned int* __restrict__ ei, int* __restrict__ flag) {
  unsigned int v = ei[2 * threadIdx.x + 1];
  unsigned long long b = __ballot(v != 0u);
  if (threadIdx.x == 0) *flag = (b == 0ull) ? 1 : 0;
}

__device__ __forceinline__ int edge_val(const void* ei, int is64, long long idx) {
  if (is64) return (int)((const long long*)ei)[idx];
  return ((const int*)ei)[idx];
}

// ---------------------------------------------------------------- degree / CSR

__global__ void hist_kernel(const void* __restrict__ ei, const int* __restrict__ flag,
                            int* __restrict__ counts) {
  const int is64 = *flag;
  for (long long e = (long long)blockIdx.x * blockDim.x + threadIdx.x; e < NEDGES;
       e += (long long)gridDim.x * blockDim.x) {
    int d = edge_val(ei, is64, NEDGES + e);
    atomicAdd(&counts[d], 1);
  }
}

__global__ void dinv_kernel(const int* __restrict__ counts, float* __restrict__ dinv) {
  int i = blockIdx.x * blockDim.x + threadIdx.x;
  if (i < NNODES) dinv[i] = rsqrtf((float)(counts[i] + 1));  // +1 self loop
}

#define SCAN_B 256
#define SCAN_TILE 1024

__global__ void scan_reduce_kernel(const int* __restrict__ counts, int* __restrict__ bsums) {
  __shared__ int sd[SCAN_B];
  int t = threadIdx.x;
  int base = blockIdx.x * SCAN_TILE + t * 4;
  int s = 0;
#pragma unroll
  for (int i = 0; i < 4; i++) {
    int idx = base + i;
    if (idx < NNODES) s += counts[idx];
  }
  sd[t] = s;
  __syncthreads();
  for (int o = SCAN_B / 2; o > 0; o >>= 1) {
    if (t < o) sd[t] += sd[t + o];
    __syncthreads();
  }
  if (t == 0) bsums[blockIdx.x] = sd[0];
}

__global__ void scan_bsums_kernel(int* __restrict__ bsums, int* __restrict__ offs, int nb) {
  if (threadIdx.x == 0 && blockIdx.x == 0) {
    int run = 0;
    for (int b = 0; b < nb; b++) {
      int v = bsums[b];
      bsums[b] = run;
      run += v;
    }
    offs[NNODES] = run;
  }
}

__global__ void scan_write_kernel(const int* __restrict__ counts, const int* __restrict__ bsums,
                                  int* __restrict__ offs) {
  __shared__ int sd[SCAN_B];
  int t = threadIdx.x;
  int base = blockIdx.x * SCAN_TILE + t * 4;
  int v[4];
  int s = 0;
#pragma unroll
  for (int i = 0; i < 4; i++) {
    int idx = base + i;
    v[i] = (idx < NNODES) ? counts[idx] : 0;
    s += v[i];
  }
  sd[t] = s;
  __syncthreads();
  for (int o = 1; o < SCAN_B; o <<= 1) {
    int x = (t >= o) ? sd[t - o] : 0;
    __syncthreads();
    sd[t] += x;
    __syncthreads();
  }
  int run = sd[t] - s + bsums[blockIdx.x];
#pragma unroll
  for (int i = 0; i < 4; i++) {
    int idx = base + i;
    if (idx < NNODES) {
      offs[idx] = run;
      run += v[i];
    }
  }
}

__global__ void fill_kernel(const void* __restrict__ ei, const int* __restrict__ flag,
                            const int* __restrict__ offs, int* __restrict__ fillc,
                            int* __restrict__ csr) {
  const int is64 = *flag;
  for (long long e = (long long)blockIdx.x * blockDim.x + threadIdx.x; e < NEDGES;
       e += (long long)gridDim.x * blockDim.x) {
    int s = edge_val(ei, is64, e);
    int d = edge_val(ei, is64, NEDGES + e);
    int pos = offs[d] + atomicAdd(&fillc[d], 1);
    csr[pos] = s;
  }
}

// ---------------------------------------------------------------- prescale (fp16 out)
// y[i,:] = (fp16) dinv[i] * x[i,:]

__global__ void prescale_half_kernel(const float* __restrict__ x, const float* __restrict__ dinv,
                                     f16x4* __restrict__ y) {
  int i = blockIdx.x * blockDim.x + threadIdx.x;  // over NNODES*32 float4
  if (i >= NNODES * 32) return;
  int row = i >> 5;
  float s = dinv[row];
  float4 v = ((const float4*)x)[i];
  f16x4 h;
  h[0] = (_Float16)(v.x * s);
  h[1] = (_Float16)(v.y * s);
  h[2] = (_Float16)(v.z * s);
  h[3] = (_Float16)(v.w * s);
  y[i] = h;
}

// ---------------------------------------------------------------- aggregation (gather, fp16 in)
// Input rows are PRE-SCALED fp16: y_j = (fp16)(dinv[j]*x_j).   256 B/row.
// out[i,:] = dinv[i] * (y_i + sum_{j in nbr(i)} y_j) + bias   (fp32 accumulate)
// out_half: write fp16 (feeds the next GEMM's fp16 A path), else fp32.
// One wave per node, f16x2 per lane, 8-way unrolled gathers (4 fp32 accumulators).

__device__ __forceinline__ float2 f16x2_to_f32(f16x2 h) {
  return make_float2((float)h[0], (float)h[1]);
}

__global__ __launch_bounds__(256) void aggregate_half_kernel(
    const f16x2* __restrict__ in, void* __restrict__ out, int out_half,
    const int* __restrict__ offs, const int* __restrict__ csr, const float* __restrict__ dinv,
    const float* __restrict__ bias) {
  int node = blockIdx.x * 4 + (threadIdx.x >> 6);
  if (node >= NNODES) return;
  int ch = threadIdx.x & 63;  // f16x2 index within row (64 x f16x2 = 128 cols)
  int beg = offs[node], end = offs[node + 1];

  // self term (pre-scaled row)
  float2 a0 = f16x2_to_f32(in[(size_t)node * 64 + ch]);
  float2 a1 = make_float2(0.f, 0.f);
  float2 a2 = make_float2(0.f, 0.f);
  float2 a3 = make_float2(0.f, 0.f);

  int p = beg;
  for (; p + 8 <= end; p += 8) {
    int j0 = csr[p + 0], j1 = csr[p + 1], j2 = csr[p + 2], j3 = csr[p + 3];
    int j4 = csr[p + 4], j5 = csr[p + 5], j6 = csr[p + 6], j7 = csr[p + 7];
    f16x2 h0 = in[(size_t)j0 * 64 + ch];
    f16x2 h1 = in[(size_t)j1 * 64 + ch];
    f16x2 h2 = in[(size_t)j2 * 64 + ch];
    f16x2 h3 = in[(size_t)j3 * 64 + ch];
    f16x2 h4 = in[(size_t)j4 * 64 + ch];
    f16x2 h5 = in[(size_t)j5 * 64 + ch];
    f16x2 h6 = in[(size_t)j6 * 64 + ch];
    f16x2 h7 = in[(size_t)j7 * 64 + ch];
    float2 v0 = f16x2_to_f32(h0);
    float2 v1 = f16x2_to_f32(h1);
    float2 v2 = f16x2_to_f32(h2);
    float2 v3 = f16x2_to_f32(h3);
    float2 v4 = f16x2_to_f32(h4);
    float2 v5 = f16x2_to_f32(h5);
    float2 v6 = f16x2_to_f32(h6);
    float2 v7 = f16x2_to_f32(h7);
    a0.x += v0.x; a0.y += v0.y;
    a1.x += v1.x; a1.y += v1.y;
    a2.x += v2.x; a2.y += v2.y;
    a3.x += v3.x; a3.y += v3.y;
    a0.x += v4.x; a0.y += v4.y;
    a1.x += v5.x; a1.y += v5.y;
    a2.x += v6.x; a2.y += v6.y;
    a3.x += v7.x; a3.y += v7.y;
  }
  for (; p + 2 <= end; p += 2) {
    int j0 = csr[p], j1 = csr[p + 1];
    float2 v0 = f16x2_to_f32(in[(size_t)j0 * 64 + ch]);
    float2 v1 = f16x2_to_f32(in[(size_t)j1 * 64 + ch]);
    a0.x += v0.x; a0.y += v0.y;
    a1.x += v1.x; a1.y += v1.y;
  }
  if (p < end) {
    float2 v0 = f16x2_to_f32(in[(size_t)csr[p] * 64 + ch]);
    a0.x += v0.x; a0.y += v0.y;
  }

  float di = dinv[node];
  int c = ch * 2;
  float2 r;
  r.x = di * (a0.x + a1.x + a2.x + a3.x);
  r.y = di * (a0.y + a1.y + a2.y + a3.y);
  if (bias) {
    r.x += bias[c];
    r.y += bias[c + 1];
  }
  if (out_half) {
    f16x2 h;
    h[0] = (_Float16)r.x;
    h[1] = (_Float16)r.y;
    ((f16x2*)out)[(size_t)node * 64 + ch] = h;
  } else {
    *(float2*)((float*)out + (size_t)node * 128 + c) = r;
  }
}

// ---------------------------------------------------------------- weight prep
// W [K][M] fp32  ->  Wt_h/Wt_l [M][K] fp16 (transposed, split: w = wh + wl, wl ~ 2^-11 w)

__global__ void wprep_f16_kernel(const float* __restrict__ W, int K, int M,
                                 _Float16* __restrict__ th, _Float16* __restrict__ tl) {
  int i = blockIdx.x * blockDim.x + threadIdx.x;
  if (i >= K * M) return;
  int k = i / M, m = i - k * M;
  float x = W[i];
  _Float16 h = (_Float16)x;
  th[(size_t)m * K + k] = h;
  tl[(size_t)m * K + k] = (_Float16)(x - (float)h);
}

// ---------------------------------------------------------------- fp16x2 split MFMA GEMM
// C[n,M] = concat(A0,A1,A2) @ W (+row_scale)(+bias)(+relu).
// A chunks may be fp32 (t=0, converted to fp16 at staging) or fp16 (t=1, pure copy).
// W split into fp16 hi/lo: a*w ~= a*wh + a*wl (2 MFMAs, fp32 accumulate).
// Residual error ~2^-12 relative (a's fp16 rounding) — well under output tolerance.
// Block 128x128, BK=32, 4 waves each 64x64 (4x4 tiles of 16x16x32 f16 MFMA).
// row_scale: C[r,:] *= row_scale[r] before bias (folds dinv pre-scale of next agg).
// out_half: write fp16 (feeds fp16 A path / aggregation), else fp32.

#define BM 128
#define BN 128
#define BK 32
#define LDT 40

__global__ __launch_bounds__(256) void gemm_f16_kernel(
    const void* __restrict__ A0, int K0, int t0, const void* __restrict__ A1, int K1, int t1,
    const void* __restrict__ A2, int K2, int t2, const _Float16* __restrict__ Bth,
    const _Float16* __restrict__ Btl, int Ktot, int M, const float* __restrict__ bias,
    const float* __restrict__ row_scale, void* __restrict__ Cmat, int relu, int out_half,
    int nrows) {
  __shared__ unsigned short As[BM * LDT];
  __shared__ unsigned short Bs_h[BN * LDT];
  __shared__ unsigned short Bs_l[BN * LDT];

  const int tid = threadIdx.x;
  const int lane = tid & 63;
  const int wv = tid >> 6;
  const int mBase = (wv >> 1) * 64;
  const int nBase = (wv & 1) * 64;
  const int ml = lane & 15;
  const int quad = lane >> 4;
  const int rowBase = blockIdx.x * BM;
  const int colBase = blockIdx.y * BN;

  const int sr = tid >> 1;         // 0..127
  const int skc = (tid & 1) * 16;  // 0 or 16 (halfs)

  f32x4 acc[4][4];
  const f32x4 zero = {0.f, 0.f, 0.f, 0.f};
#pragma unroll
  for (int i = 0; i < 4; i++)
#pragma unroll
    for (int j = 0; j < 4; j++) acc[i][j] = zero;

  for (int k0 = 0; k0 < Ktot; k0 += BK) {
    const void* Ap;
    int kl, Kp, tp;
    if (k0 < K0) {
      Ap = A0; kl = k0; Kp = K0; tp = t0;
    } else if (k0 < K0 + K1) {
      Ap = A1; kl = k0 - K0; Kp = K1; tp = t1;
    } else {
      Ap = A2; kl = k0 - K0 - K1; Kp = K2; tp = t2;
    }
    {
      int gr = rowBase + sr;
      if (gr < nrows) {
        if (tp == 0) {
          // fp32 source: load 16 floats, convert to fp16
          const float* src = (const float*)Ap + (size_t)gr * Kp + kl + skc;
          float4 v0 = ((const float4*)src)[0];
          float4 v1 = ((const float4*)src)[1];
          float4 v2 = ((const float4*)src)[2];
          float4 v3 = ((const float4*)src)[3];
          f16x8 h0, h1;
          h0[0] = (_Float16)v0.x; h0[1] = (_Float16)v0.y;
          h0[2] = (_Float16)v0.z; h0[3] = (_Float16)v0.w;
          h0[4] = (_Float16)v1.x; h0[5] = (_Float16)v1.y;
          h0[6] = (_Float16)v1.z; h0[7] = (_Float16)v1.w;
          h1[0] = (_Float16)v2.x; h1[1] = (_Float16)v2.y;
          h1[2] = (_Float16)v2.z; h1[3] = (_Float16)v2.w;
          h1[4] = (_Float16)v3.x; h1[5] = (_Float16)v3.y;
          h1[6] = (_Float16)v3.z; h1[7] = (_Float16)v3.w;
          *(f16x8*)&As[sr * LDT + skc] = h0;
          *(f16x8*)&As[sr * LDT + skc + 8] = h1;
        } else {
          // fp16 source: pure 32B copy
          const uint4* src = (const uint4*)((const _Float16*)Ap + (size_t)gr * Kp + kl + skc);
          *(uint4*)&As[sr * LDT + skc] = src[0];
          *(uint4*)&As[sr * LDT + skc + 8] = src[1];
        }
      } else {
        uint4 z = make_uint4(0u, 0u, 0u, 0u);
        *(uint4*)&As[sr * LDT + skc] = z;
        *(uint4*)&As[sr * LDT + skc + 8] = z;
      }

      const _Float16* bh = Bth + (size_t)(colBase + sr) * Ktot + k0 + skc;
      const _Float16* bl = Btl + (size_t)(colBase + sr) * Ktot + k0 + skc;
      uint4 u0 = ((const uint4*)bh)[0];
      uint4 u1 = ((const uint4*)bh)[1];
      uint4 w0 = ((const uint4*)bl)[0];
      uint4 w1 = ((const uint4*)bl)[1];
      *(uint4*)&Bs_h[sr * LDT + skc] = u0;
      *(uint4*)&Bs_h[sr * LDT + skc + 8] = u1;
      *(uint4*)&Bs_l[sr * LDT + skc] = w0;
      *(uint4*)&Bs_l[sr * LDT + skc + 8] = w1;
    }
    __syncthreads();

    f16x8 av[4], bh[4], bl[4];
#pragma unroll
    for (int nt = 0; nt < 4; nt++) {
      int nrow = nBase + nt * 16 + ml;
      bh[nt] = *(const f16x8*)&Bs_h[nrow * LDT + quad * 8];
      bl[nt] = *(const f16x8*)&Bs_l[nrow * LDT + quad * 8];
    }
#pragma unroll
    for (int mt = 0; mt < 4; mt++) {
      int mrow = mBase + mt * 16 + ml;
      av[mt] = *(const f16x8*)&As[mrow * LDT + quad * 8];
    }
#pragma unroll
    for (int mt = 0; mt < 4; mt++)
#pragma unroll
      for (int nt = 0; nt < 4; nt++) {
        acc[mt][nt] = __builtin_amdgcn_mfma_f32_16x16x32_f16(av[mt], bh[nt], acc[mt][nt], 0, 0, 0);
        acc[mt][nt] = __builtin_amdgcn_mfma_f32_16x16x32_f16(av[mt], bl[nt], acc[mt][nt], 0, 0, 0);
      }
    __syncthreads();
  }

  // epilogue: C/D layout col=lane&15, row=quad*4+reg
#pragma unroll
  for (int nt = 0; nt < 4; nt++) {
    int col = colBase + nBase + nt * 16 + ml;
    float bv = bias ? bias[col] : 0.f;
#pragma unroll
    for (int mt = 0; mt < 4; mt++) {
      int row0 = rowBase + mBase + mt * 16 + quad * 4;
#pragma unroll
      for (int r = 0; r < 4; r++) {
        int grow = row0 + r;
        if (grow >= nrows) continue;
        float v = acc[mt][nt][r];
        if (row_scale) v *= row_scale[grow];
        v += bv;
        if (relu) v = fmaxf(v, 0.f);
        if (out_half) {
          ((_Float16*)Cmat)[(size_t)grow * M + col] = (_Float16)v;
        } else {
          ((float*)Cmat)[(size_t)grow * M + col] = v;
        }
      }
    }
  }
}

// ---------------------------------------------------------------- launch

extern "C" void kernel_launch(void* const* d_in, const int* in_sizes, int n_in, void* d_out,
                              int out_size, void* d_ws, size_t ws_size, hipStream_t stream) {
  const float* x_self     = (const float*)d_in[0];
  const float* x_neighbor = (const float*)d_in[1];
  const void*  edge_index = d_in[2];
  const float* W_in_self  = (const float*)d_in[3];
  const float* b_in_self  = (const float*)d_in[4];
  const float* W_out_self = (const float*)d_in[5];
  const float* b_out_self = (const float*)d_in[6];
  const float* Wg1        = (const float*)d_in[7];
  const float* bg1        = (const float*)d_in[8];
  const float* Wg2        = (const float*)d_in[9];
  const float* bg2        = (const float*)d_in[10];
  const float* W_out      = (const float*)d_in[11];
  const float* b_out      = (const float*)d_in[12];
  float* out = (float*)d_out;

  char* ws = (char*)d_ws;
  size_t off = 0;
  auto alloc = [&](size_t bytes) -> void* {
    void* p = ws + off;
    off = (off + bytes + 255) & ~(size_t)255;
    return p;
  };
  int* counts = (int*)alloc((size_t)2 * NNODES * 4);  // counts + fillc contiguous
  int* fillc  = counts + NNODES;
  int*   offs   = (int*)alloc((size_t)(NNODES + 1) * 4);
  int*   csr    = (int*)alloc((size_t)NEDGES * 4);
  int*   bsums  = (int*)alloc(4096);
  int*   flag   = (int*)alloc(256);
  float* dinv   = (float*)alloc((size_t)NNODES * 4);
  _Float16* wt1h = (_Float16*)alloc(32768 * 2);  // W_in_self  K=128 M=256
  _Float16* wt1l = (_Float16*)alloc(32768 * 2);
  _Float16* wt2h = (_Float16*)alloc(49152 * 2);  // W_out_self K=384 M=128
  _Float16* wt2l = (_Float16*)alloc(49152 * 2);
  _Float16* wt3h = (_Float16*)alloc(32768 * 2);  // Wg1        K=128 M=256
  _Float16* wt3l = (_Float16*)alloc(32768 * 2);
  _Float16* wt4h = (_Float16*)alloc(32768 * 2);  // Wg2        K=256 M=128
  _Float16* wt4l = (_Float16*)alloc(32768 * 2);
  _Float16* wt5h = (_Float16*)alloc(65536 * 2);  // W_out      K=512 M=128
  _Float16* wt5l = (_Float16*)alloc(65536 * 2);
  float* bufA = (float*)alloc((size_t)NNODES * 256 * 4);
  float* bufB = (float*)alloc((size_t)NNODES * 256 * 4);
  (void)ws_size;

  const int nb = (NNODES + SCAN_TILE - 1) / SCAN_TILE;  // 98
  const int gridRows = (NNODES + BM - 1) / BM;          // 782

  detect_kernel<<<1, 64, 0, stream>>>((const unsigned int*)edge_index, flag);
  zero_int_kernel<<<(2 * NNODES + 255) / 256, 256, 0, stream>>>(counts, 2 * NNODES);
  hist_kernel<<<1024, 256, 0, stream>>>(edge_index, flag, counts);
  dinv_kernel<<<(NNODES + 255) / 256, 256, 0, stream>>>(counts, dinv);
  scan_reduce_kernel<<<nb, SCAN_B, 0, stream>>>(counts, bsums);
  scan_bsums_kernel<<<1, 64, 0, stream>>>(bsums, offs, nb);
  scan_write_kernel<<<nb, SCAN_B, 0, stream>>>(counts, bsums, offs);
  fill_kernel<<<1024, 256, 0, stream>>>(edge_index, flag, offs, fillc, csr);

  wprep_f16_kernel<<<(32768 + 255) / 256, 256, 0, stream>>>(W_in_self, 128, 256, wt1h, wt1l);
  wprep_f16_kernel<<<(49152 + 255) / 256, 256, 0, stream>>>(W_out_self, 384, 128, wt2h, wt2l);
  wprep_f16_kernel<<<(32768 + 255) / 256, 256, 0, stream>>>(Wg1, 128, 256, wt3h, wt3l);
  wprep_f16_kernel<<<(32768 + 255) / 256, 256, 0, stream>>>(Wg2, 256, 128, wt4h, wt4l);
  wprep_f16_kernel<<<(65536 + 255) / 256, 256, 0, stream>>>(W_out, 512, 128, wt5h, wt5l);

  // ---- dense self branch ----
  // l1 = relu(x_self @ W1 + b1) stored fp16 [N,256] in bufA
  _Float16* l1 = (_Float16*)bufA;
  gemm_f16_kernel<<<dim3(gridRows, 2), 256, 0, stream>>>(
      x_self, 128, 0, nullptr, 0, 0, nullptr, 0, 0, wt1h, wt1l, 128, 256, b_in_self, nullptr,
      l1, 1, 1, NNODES);
  gemm_f16_kernel<<<dim3(gridRows, 1), 256, 0, stream>>>(
      x_self, 128, 0, l1, 256, 1, nullptr, 0, 0, wt2h, wt2l, 384, 128, b_out_self, nullptr,
      out, 0, 0, NNODES);

  // ---- GCN branch (A_norm @ (X W) == (A_norm @ X) W), all intermediates fp16 ----
  // Buffer timeline:
  //   ybuf = bufB [N,128] f16 (dead after agg1)
  //   aggx = bufA [N,128] f16 (bufA free after GEMM-2; dead after GEMM-3)
  //   g1   = bufB [N,256] f16 (overwrites ybuf; live through GEMM-5)
  //   xw2  = bufA [N,128] f16 (dead after agg2)
  //   g2   = bufA + N*128 halfs, [N,128] f16 (no overlap with xw2)
  _Float16* ybuf = (_Float16*)bufB;
  _Float16* aggx = (_Float16*)bufA;
  _Float16* g1   = (_Float16*)bufB;
  _Float16* xw2  = (_Float16*)bufA;
  _Float16* g2   = (_Float16*)bufA + (size_t)NNODES * 128;

  prescale_half_kernel<<<(NNODES * 32 + 255) / 256, 256, 0, stream>>>(x_neighbor, dinv,
                                                                     (f16x4*)ybuf);
  aggregate_half_kernel<<<NNODES / 4, 256, 0, stream>>>((const f16x2*)ybuf, aggx, 1, offs, csr,
                                                        dinv, nullptr);
  gemm_f16_kernel<<<dim3(gridRows, 2), 256, 0, stream>>>(
      aggx, 128, 1, nullptr, 0, 0, nullptr, 0, 0, wt3h, wt3l, 128, 256, bg1, nullptr, g1, 0, 1,
      NNODES);
  // xw2 = (fp16)((g1 @ Wg2) * dinv[row])  (pre-scale for agg2 folded into epilogue)
  gemm_f16_kernel<<<dim3(gridRows, 1), 256, 0, stream>>>(
      g1, 256, 1, nullptr, 0, 0, nullptr, 0, 0, wt4h, wt4l, 256, 128, nullptr, dinv, xw2, 0, 1,
      NNODES);
  aggregate_half_kernel<<<NNODES / 4, 256, 0, stream>>>((const f16x2*)xw2, g2, 1, offs, csr,
                                                        dinv, bg2);
  gemm_f16_kernel<<<dim3(gridRows, 1), 256, 0, stream>>>(
      x_neighbor, 128, 0, g1, 256, 1, g2, 128, 1, wt5h, wt5l, 512, 128, b_out, nullptr,
      out + (size_t)NNODES * 128, 0, 0, NNODES);
}